// Round 2
// 306.161 us; speedup vs baseline: 1.0011x; 1.0011x over previous
//
#include <hip/hip_runtime.h>
#include <hip/hip_bf16.h>
#include <stdint.h>

// Problem constants (head_2327872274482): B=1024, T=256, C=195, H=8
#define TT   256
#define CC   195
#define HH   8
#define NKT  7     // projection K-tiles of 32 (7*32 = 224 >= 195)
#define VSTR 260   // Vt row stride (shorts): 130 words -> ~4-way max on b64 reads

typedef __attribute__((ext_vector_type(8))) short short8;   // bf16 MFMA A/B frag
typedef __attribute__((ext_vector_type(4))) short short4v;  // half-frag (8 B)
typedef __attribute__((ext_vector_type(4))) float f32x4;    // MFMA C/D frag

static __device__ __forceinline__ short f2bf(float v) {
    union { __hip_bfloat16 h; short s; } cv;
    cv.h = __float2bfloat16(v);
    return cv.s;
}

// LDS: Ql 4096 + Kl 4096 + Vt 8320 = 16.5 KB; VGPR<=128 -> 4 blocks/CU,
// grid 1024 = 4/CU fully co-resident.
//
// Attention uses SWAPPED QK^T: S^T = mfma(A=K, B=Q) so each lane holds the
// P-values of its own q-column (S^T[key=quad*4+r][q=nn]). P then feeds the
// PV mfma as a register-resident A-frag with keymap k=quad*8+j ->
// key = kb + (j>>2)*16 + quad*4 + (j&3); V frag loaded with the same keymap.
// -> no P LDS round-trip, no lgkmcnt(0) drains, no compiler barriers.
__global__ __launch_bounds__(256, 4)
void fused_head(const float* __restrict__ x,
                const float* __restrict__ Wq,
                const float* __restrict__ Wk,
                const float* __restrict__ Wv,
                float* __restrict__ out)
{
    __shared__ short Ql[TT * 8];          // Q rows, 8 bf16 features (16 B/row)
    __shared__ short Kl[TT * 8];          // K rows, same
    __shared__ short Vt[16 * VSTR];       // V transposed: row n<8 = v_h; n=8 = 1.0; n>8 = 0

    const int tid  = threadIdx.x;
    const int lane = tid & 63;
    const int wv   = __builtin_amdgcn_readfirstlane(tid >> 6);
    const int b    = blockIdx.x;
    const int nn   = lane & 15;
    const int quad = lane >> 4;

    // ---- init Vt rows 8..15: row 8 = ones (denom column), rows 9..15 = 0
    {
        uint32_t* vtw = (uint32_t*)Vt;
        const int base = (8 * VSTR) / 2;
        for (int i = tid; i < (8 * VSTR) / 2; i += 256)
            vtw[base + i] = (i < VSTR / 2) ? 0x3F803F80u : 0u;
    }

    const float* __restrict__ xb = x + (size_t)b * (TT * CC);

    // ---- projection B-frag preload (verified layout: B[k=quad*8+j][n=lane&15])
    const float* Wsel0 = (nn < 8) ? (Wq + nn) : (Wk + nn - 8);
    const float* Wsel1 = (nn < 8) ? (Wv + nn) : nullptr;
    short8 Bf[NKT][2];
#pragma unroll
    for (int kt = 0; kt < NKT; ++kt) {
#pragma unroll
        for (int j = 0; j < 8; ++j) {
            const int k = kt * 32 + quad * 8 + j;
            float v0 = (k < CC) ? Wsel0[(size_t)k * HH] : 0.f;
            float v1 = (k < CC && Wsel1) ? Wsel1[(size_t)k * HH] : 0.f;
            Bf[kt][0][j] = f2bf(v0);
            Bf[kt][1][j] = f2bf(v1);
        }
    }

    // ---- projection: A-frags straight from global (LDS-free), MFMA, then store
    // q/k/v into attention-ready bf16 LDS layouts.
    for (int ch = 0; ch < 4; ++ch) {
        const int rbase = ch * 64 + wv * 16;
        const float* __restrict__ xrow = xb + (size_t)(rbase + nn) * CC;

        f32x4 acc0 = {0.f, 0.f, 0.f, 0.f};
        f32x4 acc1 = {0.f, 0.f, 0.f, 0.f};
#pragma unroll
        for (int kt = 0; kt < NKT; ++kt) {
            float f[8];
#pragma unroll
            for (int j = 0; j < 8; ++j) {
                const int k = kt * 32 + quad * 8 + j;
                f[j] = (k < CC) ? xrow[k] : 0.f;
            }
            short8 a;
#pragma unroll
            for (int j = 0; j < 8; ++j) a[j] = f2bf(f[j]);
            acc0 = __builtin_amdgcn_mfma_f32_16x16x32_bf16(a, Bf[kt][0], acc0, 0, 0, 0);
            acc1 = __builtin_amdgcn_mfma_f32_16x16x32_bf16(a, Bf[kt][1], acc1, 0, 0, 0);
        }
        // C/D layout: col = lane&15, row = quad*4 + reg
#pragma unroll
        for (int r = 0; r < 4; ++r) {
            const int trow = rbase + quad * 4 + r;
            const short qs = f2bf(acc0[r]);
            if (nn < 8) {
                Ql[trow * 8 + nn] = qs;                  // Q[row][feature]
                Vt[nn * VSTR + trow] = f2bf(acc1[r]);    // Vt[feature][key]
            } else {
                Kl[trow * 8 + (nn - 8)] = qs;            // K[row][feature]
            }
        }
    }
    __syncthreads();   // only barrier: proj -> attention

    // ---- MFMA attention, register-resident P. Wave wv owns q-tiles
    // {wv, 7-wv, 8+wv, 15-wv} (each set sums to 18 chunks -> balanced waves).
    const float SC2 = 0.07161149f * 1.44269504f;   // (1/sqrt(195)) * log2(e)
    const int qt4[4] = { wv, 7 - wv, 8 + wv, 15 - wv };

    for (int qi = 0; qi < 4; ++qi) {
        const int qt = qt4[qi];
        const int qb = qt * 16;
        const int qcol = qb + nn;                 // this lane's q (S^T column)

        short8 bQ = (short8){0, 0, 0, 0, 0, 0, 0, 0};
        if (quad == 0)
            bQ = *reinterpret_cast<const short8*>(Ql + (qb + nn) * 8);

        f32x4 accO = {0.f, 0.f, 0.f, 0.f};       // cols: 0..7 = o_h, 8 = denom
        const int nch = (qt >> 1) + 1;            // 32-key chunks covering keys<=qb+15
        for (int c = 0; c < nch; ++c) {
            const int kb = c * 32;
            // half-1 of the diagonal chunk of even q-tiles is fully masked: skip it
            const bool doH1 = (c < nch - 1) || (qt & 1);

            // S^T = K . Q^T : rows = keys, cols = q
            short8 aK0 = (short8){0, 0, 0, 0, 0, 0, 0, 0};
            short8 aK1 = (short8){0, 0, 0, 0, 0, 0, 0, 0};
            if (quad == 0) {
                aK0 = *reinterpret_cast<const short8*>(Kl + (kb + nn) * 8);
                if (doH1)
                    aK1 = *reinterpret_cast<const short8*>(Kl + (kb + 16 + nn) * 8);
            }
            f32x4 s0 = __builtin_amdgcn_mfma_f32_16x16x32_bf16(
                           aK0, bQ, (f32x4){0.f, 0.f, 0.f, 0.f}, 0, 0, 0);
            f32x4 s1 = {0.f, 0.f, 0.f, 0.f};
            if (doH1)
                s1 = __builtin_amdgcn_mfma_f32_16x16x32_bf16(
                         aK1, bQ, (f32x4){0.f, 0.f, 0.f, 0.f}, 0, 0, 0);

            // V fragment with the same keymap (8B loads, 8B-aligned: VSTR%4==0)
            const short* vrow = Vt + nn * VSTR + kb + quad * 4;
            const short4v v0 = *reinterpret_cast<const short4v*>(vrow);
            const short4v v1 = *reinterpret_cast<const short4v*>(vrow + 16);

            const int keyb = kb + quad * 4;       // this lane's first key (half 0)
            short8 aP, bV;
#pragma unroll
            for (int r = 0; r < 4; ++r) {
                const float e0 = (keyb + r <= qcol) ? exp2f(s0[r] * SC2) : 0.f;
                const float e1 = (doH1 && (keyb + 16 + r <= qcol))
                                     ? exp2f(s1[r] * SC2) : 0.f;
                aP[r]     = f2bf(e0);
                aP[4 + r] = f2bf(e1);
                bV[r]     = v0[r];
                bV[4 + r] = v1[r];
            }
            accO = __builtin_amdgcn_mfma_f32_16x16x32_bf16(aP, bV, accO, 0, 0, 0);
        }

        // epilogue: denom sits in col n=8 of the same C-layout row
#pragma unroll
        for (int r = 0; r < 4; ++r) {
            const float dn = __shfl(accO[r], (lane & 48) | 8);
            if (nn < 8) {
                const int q = qb + quad * 4 + r;
                out[((size_t)b * TT + q) * HH + nn] = accO[r] / dn;
            }
        }
    }
}

extern "C" void kernel_launch(void* const* d_in, const int* in_sizes, int n_in,
                              void* d_out, int out_size, void* d_ws, size_t ws_size,
                              hipStream_t stream)
{
    const float* x  = (const float*)d_in[0];
    const float* Wq = (const float*)d_in[1];
    const float* Wk = (const float*)d_in[2];
    const float* Wv = (const float*)d_in[3];
    float* out      = (float*)d_out;
    const int B = in_sizes[0] / (TT * CC);   // = 1024
    fused_head<<<dim3(B), dim3(256), 0, stream>>>(x, Wq, Wk, Wv, out);
}

// Round 3
// 305.512 us; speedup vs baseline: 1.0032x; 1.0021x over previous
//
#include <hip/hip_runtime.h>
#include <hip/hip_bf16.h>
#include <stdint.h>

// Problem constants (head_2327872274482): B=1024, T=256, C=195, H=8
#define TT   256
#define CC   195
#define HH   8
#define NKT  7     // projection K-tiles of 32 (7*32 = 224 >= 195)
#define VSTR 260   // Vt row stride (shorts): 130 words -> ~4-way max on b64 reads

typedef __attribute__((ext_vector_type(8))) short short8;   // bf16 MFMA A/B frag
typedef __attribute__((ext_vector_type(4))) short short4v;  // half-frag (8 B)
typedef __attribute__((ext_vector_type(4))) float f32x4;    // MFMA C/D frag

static __device__ __forceinline__ short f2bf(float v) {
    union { __hip_bfloat16 h; short s; } cv;
    cv.h = __float2bfloat16(v);
    return cv.s;
}

// LDS: Ql 4096 + Kl 4096 + Vt 8320 = 16.5 KB; VGPR<=128 -> 4 blocks/CU,
// grid 1024 = 4/CU fully co-resident.
//
// PIPELINED SCHEDULE (causal structure permits):
//   proj(0) | bar | proj(1)+attn(qt 0-3) | bar | proj(2)+attn(qt 4-7) | bar
//           | proj(3)+attn(qt 8-11) | bar | attn(qt 12-15)
// proj(ch) writes rows 64ch..64ch+63; attn stage s reads rows < 64(s+1)
// (Q rows qb..qb+15 and keys <= qb+15, both < 64(s+1)) -> disjoint from the
// concurrent proj writes, RAW protected by the preceding barrier.
// Attention uses SWAPPED QK^T (S^T = mfma(K,Q)): P stays register-resident,
// no LDS round-trip -> the barrier-free regions let proj loads overlap attn.
__global__ __launch_bounds__(256, 4)
void fused_head(const float* __restrict__ x,
                const float* __restrict__ Wq,
                const float* __restrict__ Wk,
                const float* __restrict__ Wv,
                float* __restrict__ out)
{
    __shared__ short Ql[TT * 8];          // Q rows, 8 bf16 features (16 B/row)
    __shared__ short Kl[TT * 8];          // K rows, same
    __shared__ short Vt[16 * VSTR];       // V transposed: row n<8 = v_h; n=8 = 1.0; n>8 = 0

    const int tid  = threadIdx.x;
    const int lane = tid & 63;
    const int wv   = __builtin_amdgcn_readfirstlane(tid >> 6);
    const int b    = blockIdx.x;
    const int nn   = lane & 15;
    const int quad = lane >> 4;

    // ---- init Vt rows 8..15: row 8 = ones (denom column), rows 9..15 = 0
    {
        uint32_t* vtw = (uint32_t*)Vt;
        const int base = (8 * VSTR) / 2;
        for (int i = tid; i < (8 * VSTR) / 2; i += 256)
            vtw[base + i] = (i < VSTR / 2) ? 0x3F803F80u : 0u;
    }

    const float* __restrict__ xb = x + (size_t)b * (TT * CC);

    // ---- projection B-frag preload (verified layout: B[k=quad*8+j][n=lane&15])
    const float* Wsel0 = (nn < 8) ? (Wq + nn) : (Wk + nn - 8);
    const float* Wsel1 = (nn < 8) ? (Wv + nn) : nullptr;
    short8 Bf[NKT][2];
#pragma unroll
    for (int kt = 0; kt < NKT; ++kt) {
#pragma unroll
        for (int j = 0; j < 8; ++j) {
            const int k = kt * 32 + quad * 8 + j;
            float v0 = (k < CC) ? Wsel0[(size_t)k * HH] : 0.f;
            float v1 = (k < CC && Wsel1) ? Wsel1[(size_t)k * HH] : 0.f;
            Bf[kt][0][j] = f2bf(v0);
            Bf[kt][1][j] = f2bf(v1);
        }
    }

    // ---- projection of 64 rows (rows ch*64 .. ch*64+63): A-frags straight
    // from global (LDS-free), MFMA, store q/k/v into attention-ready LDS.
    auto proj_ch = [&](int ch) {
        const int rbase = ch * 64 + wv * 16;
        const float* __restrict__ xrow = xb + (size_t)(rbase + nn) * CC;

        f32x4 acc0 = {0.f, 0.f, 0.f, 0.f};
        f32x4 acc1 = {0.f, 0.f, 0.f, 0.f};
#pragma unroll
        for (int kt = 0; kt < NKT; ++kt) {
            float f[8];
#pragma unroll
            for (int j = 0; j < 8; ++j) {
                const int k = kt * 32 + quad * 8 + j;
                f[j] = (k < CC) ? xrow[k] : 0.f;
            }
            short8 a;
#pragma unroll
            for (int j = 0; j < 8; ++j) a[j] = f2bf(f[j]);
            acc0 = __builtin_amdgcn_mfma_f32_16x16x32_bf16(a, Bf[kt][0], acc0, 0, 0, 0);
            acc1 = __builtin_amdgcn_mfma_f32_16x16x32_bf16(a, Bf[kt][1], acc1, 0, 0, 0);
        }
        // C/D layout: col = lane&15, row = quad*4 + reg
#pragma unroll
        for (int r = 0; r < 4; ++r) {
            const int trow = rbase + quad * 4 + r;
            const short qs = f2bf(acc0[r]);
            if (nn < 8) {
                Ql[trow * 8 + nn] = qs;                  // Q[row][feature]
                Vt[nn * VSTR + trow] = f2bf(acc1[r]);    // Vt[feature][key]
            } else {
                Kl[trow * 8 + (nn - 8)] = qs;            // K[row][feature]
            }
        }
    };

    const float SC2 = 0.07161149f * 1.44269504f;   // (1/sqrt(195)) * log2(e)

    // ---- one q-tile of MFMA attention, register-resident P
    auto attn_tile = [&](int qt) {
        const int qb = qt * 16;
        const int qcol = qb + nn;                 // this lane's q (S^T column)

        short8 bQ = (short8){0, 0, 0, 0, 0, 0, 0, 0};
        if (quad == 0)
            bQ = *reinterpret_cast<const short8*>(Ql + (qb + nn) * 8);

        f32x4 accO = {0.f, 0.f, 0.f, 0.f};       // cols: 0..7 = o_h, 8 = denom
        const int nch = (qt >> 1) + 1;            // 32-key chunks covering keys<=qb+15
        for (int c = 0; c < nch; ++c) {
            const int kb = c * 32;
            // half-1 of the diagonal chunk of even q-tiles is fully masked: skip it
            const bool doH1 = (c < nch - 1) || (qt & 1);

            // S^T = K . Q^T : rows = keys, cols = q
            short8 aK0 = (short8){0, 0, 0, 0, 0, 0, 0, 0};
            short8 aK1 = (short8){0, 0, 0, 0, 0, 0, 0, 0};
            if (quad == 0) {
                aK0 = *reinterpret_cast<const short8*>(Kl + (kb + nn) * 8);
                if (doH1)
                    aK1 = *reinterpret_cast<const short8*>(Kl + (kb + 16 + nn) * 8);
            }
            f32x4 s0 = __builtin_amdgcn_mfma_f32_16x16x32_bf16(
                           aK0, bQ, (f32x4){0.f, 0.f, 0.f, 0.f}, 0, 0, 0);
            f32x4 s1 = {0.f, 0.f, 0.f, 0.f};
            if (doH1)
                s1 = __builtin_amdgcn_mfma_f32_16x16x32_bf16(
                         aK1, bQ, (f32x4){0.f, 0.f, 0.f, 0.f}, 0, 0, 0);

            // V fragment with the same keymap (8B loads, 8B-aligned: VSTR%4==0)
            const short* vrow = Vt + nn * VSTR + kb + quad * 4;
            const short4v v0 = *reinterpret_cast<const short4v*>(vrow);
            const short4v v1 = *reinterpret_cast<const short4v*>(vrow + 16);

            const int keyb = kb + quad * 4;       // this lane's first key (half 0)
            short8 aP, bV;
#pragma unroll
            for (int r = 0; r < 4; ++r) {
                const float e0 = (keyb + r <= qcol) ? exp2f(s0[r] * SC2) : 0.f;
                const float e1 = (doH1 && (keyb + 16 + r <= qcol))
                                     ? exp2f(s1[r] * SC2) : 0.f;
                aP[r]     = f2bf(e0);
                aP[4 + r] = f2bf(e1);
                bV[r]     = v0[r];
                bV[4 + r] = v1[r];
            }
            accO = __builtin_amdgcn_mfma_f32_16x16x32_bf16(aP, bV, accO, 0, 0, 0);
        }

        // epilogue: denom sits in col n=8 of the same C-layout row
#pragma unroll
        for (int r = 0; r < 4; ++r) {
            const float dn = __shfl(accO[r], (lane & 48) | 8);
            if (nn < 8) {
                const int q = qb + quad * 4 + r;
                out[((size_t)b * TT + q) * HH + nn] = accO[r] / dn;
            }
        }
    };

    // ---- pipelined schedule. Wave->tile maps keep cumulative chunks/wave = 18.
    proj_ch(0);
    __syncthreads();               // rows 0..63 ready
    proj_ch(1);                    // loads in flight while attn computes
    attn_tile(wv);                 // tiles 0..3   (chunks 1,1,2,2)
    __syncthreads();               // rows 0..127 ready
    proj_ch(2);
    attn_tile(4 + (wv ^ 1));       // tiles 4..7   (chunks 3,3,4,4)
    __syncthreads();               // rows 0..191 ready
    proj_ch(3);
    attn_tile(8 + (wv ^ 2));       // tiles 8..11  (chunks 6,6,5,5)
    __syncthreads();               // all rows ready
    attn_tile(12 + (wv ^ 3));      // tiles 12..15 (chunks 8,8,7,7)
}

extern "C" void kernel_launch(void* const* d_in, const int* in_sizes, int n_in,
                              void* d_out, int out_size, void* d_ws, size_t ws_size,
                              hipStream_t stream)
{
    const float* x  = (const float*)d_in[0];
    const float* Wq = (const float*)d_in[1];
    const float* Wk = (const float*)d_in[2];
    const float* Wv = (const float*)d_in[3];
    float* out      = (float*)d_out;
    const int B = in_sizes[0] / (TT * CC);   // = 1024
    fused_head<<<dim3(B), dim3(256), 0, stream>>>(x, Wq, Wk, Wv, out);
}

// Round 4
// 296.375 us; speedup vs baseline: 1.0342x; 1.0308x over previous
//
#include <hip/hip_runtime.h>
#include <hip/hip_bf16.h>
#include <stdint.h>

// Problem constants (head_2327872274482): B=1024, T=256, C=195, H=8
#define TT    256
#define CC    195
#define HH    8
#define NKT   7     // projection K-tiles of 32 (7*32 = 224 >= 195)
#define VSTR  260   // Vt row stride (shorts)
#define WSETS 14    // W fragment sets: 7 kt x {QK, V}
#define WLSTR 40    // Wl row stride in shorts (80 B = 4 quads x 16 B + 16 B pad -> 2-way banks)

typedef __attribute__((ext_vector_type(8))) short short8;   // bf16 MFMA A/B frag
typedef __attribute__((ext_vector_type(4))) short short4v;  // half-frag (8 B)
typedef __attribute__((ext_vector_type(4))) float f32x4;    // MFMA C/D frag

static __device__ __forceinline__ short f2bf(float v) {
    union { __hip_bfloat16 h; short s; } cv;
    cv.h = __float2bfloat16(v);
    return cv.s;
}

// LDS: Ql 4096 + Kl 4096 + Vt 8320 + Wl 17920 = 34.4 KB; VGPR<=128 -> 4 blocks/CU.
//
// ASYNC-STAGE SPLIT (T14): x loads for chunk ch+1 are ISSUED (to registers)
// before attn stage s and CONSUMED after it -> HBM latency hides under the
// attn compute phase. W-fragments live in LDS (Wl) to free the 56 VGPRs the
// prefetch needs. Barriers are raw s_barrier + write-side lgkmcnt(0) only —
// __syncthreads would vmcnt(0)-drain the prefetch (m97 barrier-drain).
__global__ __launch_bounds__(256, 4)
void fused_head(const float* __restrict__ x,
                const float* __restrict__ Wq,
                const float* __restrict__ Wk,
                const float* __restrict__ Wv,
                float* __restrict__ out)
{
    __shared__ __align__(16) short Ql[TT * 8];       // Q rows, 8 bf16 features
    __shared__ __align__(16) short Kl[TT * 8];       // K rows, same
    __shared__ __align__(16) short Vt[16 * VSTR];    // V^T: row n<8 = v_h; n=8 = 1.0; n>8 = 0
    __shared__ __align__(16) short Wl[WSETS * 16 * WLSTR];  // proj B-frags

    const int tid  = threadIdx.x;
    const int lane = tid & 63;
    const int wv   = __builtin_amdgcn_readfirstlane(tid >> 6);
    const int b    = blockIdx.x;
    const int nn   = lane & 15;
    const int quad = lane >> 4;

    const float* __restrict__ xb = x + (size_t)b * (TT * CC);

    float xp[NKT][8];   // prefetched x slice (56 VGPR), all indices static

    // ---- issue(ch): put chunk ch's x loads in flight (no consumption here)
    auto issue = [&](int ch) {
        const float* __restrict__ xrow = xb + (size_t)(ch * 64 + wv * 16 + nn) * CC;
#pragma unroll
        for (int kt = 0; kt < NKT; ++kt)
#pragma unroll
            for (int j = 0; j < 8; ++j) {
                const int k = kt * 32 + quad * 8 + j;
                xp[kt][j] = (k < CC) ? xrow[k] : 0.f;
            }
    };

    // ---- consume(ch): cvt + MFMA (B-frags from Wl) + store q/k/v to LDS
    auto consume = [&](int ch) {
        const int rbase = ch * 64 + wv * 16;
        f32x4 acc0 = {0.f, 0.f, 0.f, 0.f};
        f32x4 acc1 = {0.f, 0.f, 0.f, 0.f};
#pragma unroll
        for (int kt = 0; kt < NKT; ++kt) {
            short8 a;
#pragma unroll
            for (int j = 0; j < 8; ++j) a[j] = f2bf(xp[kt][j]);
            const short8 b0 = *reinterpret_cast<const short8*>(
                Wl + ((kt * 2 + 0) * 16 + nn) * WLSTR + quad * 8);
            const short8 b1 = *reinterpret_cast<const short8*>(
                Wl + ((kt * 2 + 1) * 16 + nn) * WLSTR + quad * 8);
            acc0 = __builtin_amdgcn_mfma_f32_16x16x32_bf16(a, b0, acc0, 0, 0, 0);
            acc1 = __builtin_amdgcn_mfma_f32_16x16x32_bf16(a, b1, acc1, 0, 0, 0);
        }
        // C/D layout: col = lane&15, row = quad*4 + reg
#pragma unroll
        for (int r = 0; r < 4; ++r) {
            const int trow = rbase + quad * 4 + r;
            const short qs = f2bf(acc0[r]);
            if (nn < 8) {
                Ql[trow * 8 + nn] = qs;                  // Q[row][feature]
                Vt[nn * VSTR + trow] = f2bf(acc1[r]);    // Vt[feature][key]
            } else {
                Kl[trow * 8 + (nn - 8)] = qs;            // K[row][feature]
            }
        }
    };

    const float SC2 = 0.07161149f * 1.44269504f;   // (1/sqrt(195)) * log2(e)

    // ---- one q-tile of MFMA attention, register-resident P (swapped QK^T)
    auto attn_tile = [&](int qt) {
        const int qb = qt * 16;
        const int qcol = qb + nn;                 // this lane's q (S^T column)

        short8 bQ = (short8){0, 0, 0, 0, 0, 0, 0, 0};
        if (quad == 0)
            bQ = *reinterpret_cast<const short8*>(Ql + (qb + nn) * 8);

        f32x4 accO = {0.f, 0.f, 0.f, 0.f};       // cols: 0..7 = o_h, 8 = denom
        const int nch = (qt >> 1) + 1;            // 32-key chunks covering keys<=qb+15
        for (int c = 0; c < nch; ++c) {
            const int kb = c * 32;
            const bool doH1 = (c < nch - 1) || (qt & 1);   // diagonal-half skip

            short8 aK0 = (short8){0, 0, 0, 0, 0, 0, 0, 0};
            short8 aK1 = (short8){0, 0, 0, 0, 0, 0, 0, 0};
            if (quad == 0) {
                aK0 = *reinterpret_cast<const short8*>(Kl + (kb + nn) * 8);
                if (doH1)
                    aK1 = *reinterpret_cast<const short8*>(Kl + (kb + 16 + nn) * 8);
            }
            f32x4 s0 = __builtin_amdgcn_mfma_f32_16x16x32_bf16(
                           aK0, bQ, (f32x4){0.f, 0.f, 0.f, 0.f}, 0, 0, 0);
            f32x4 s1 = {0.f, 0.f, 0.f, 0.f};
            if (doH1)
                s1 = __builtin_amdgcn_mfma_f32_16x16x32_bf16(
                         aK1, bQ, (f32x4){0.f, 0.f, 0.f, 0.f}, 0, 0, 0);

            const short* vrow = Vt + nn * VSTR + kb + quad * 4;
            const short4v v0 = *reinterpret_cast<const short4v*>(vrow);
            const short4v v1 = *reinterpret_cast<const short4v*>(vrow + 16);

            const int keyb = kb + quad * 4;
            short8 aP, bV;
#pragma unroll
            for (int r = 0; r < 4; ++r) {
                const float e0 = (keyb + r <= qcol) ? exp2f(s0[r] * SC2) : 0.f;
                const float e1 = (doH1 && (keyb + 16 + r <= qcol))
                                     ? exp2f(s1[r] * SC2) : 0.f;
                aP[r]     = f2bf(e0);
                aP[4 + r] = f2bf(e1);
                bV[r]     = v0[r];
                bV[4 + r] = v1[r];
            }
            accO = __builtin_amdgcn_mfma_f32_16x16x32_bf16(aP, bV, accO, 0, 0, 0);
        }

#pragma unroll
        for (int r = 0; r < 4; ++r) {
            const float dn = __shfl(accO[r], (lane & 48) | 8);
            if (nn < 8) {
                const int q = qb + quad * 4 + r;
                out[((size_t)b * TT + q) * HH + nn] = accO[r] / dn;
            }
        }
    };

    // LDS-visibility barrier that does NOT drain vmcnt (prefetch rides through)
    auto barrier_lds = [&]() {
        asm volatile("s_waitcnt lgkmcnt(0)" ::: "memory");
        __builtin_amdgcn_s_barrier();
        __builtin_amdgcn_sched_barrier(0);
    };

    // ================= schedule =================
    issue(0);                              // chunk-0 x loads start immediately
    __builtin_amdgcn_sched_barrier(0);

    // Vt rows 8..15: row 8 = ones (denom column), rows 9..15 = 0
    {
        uint32_t* vtw = (uint32_t*)Vt;
        const int base = (8 * VSTR) / 2;
        for (int i = tid; i < (8 * VSTR) / 2; i += 256)
            vtw[base + i] = (i < VSTR / 2) ? 0x3F803F80u : 0u;
    }
    // W-fragment preload into Wl (sets distributed across waves).
    // Verified frag layout: B[k=quad*8+j][n=lane&15]; set = kt*2 + {QK,V}
    {
        const float* Wsel0 = (nn < 8) ? (Wq + nn) : (Wk + nn - 8);
        const float* Wsel1 = Wv + (nn & 7);         // safe ptr; masked by nn<8
        for (int set = wv; set < WSETS; set += 4) {
            const int kt = set >> 1, sv = set & 1;
            short8 frag;
#pragma unroll
            for (int j = 0; j < 8; ++j) {
                const int k = kt * 32 + quad * 8 + j;
                float v = 0.f;
                if (k < CC) {
                    if (sv == 0)        v = Wsel0[(size_t)k * HH];
                    else if (nn < 8)    v = Wsel1[(size_t)k * HH];
                }
                frag[j] = f2bf(v);
            }
            *reinterpret_cast<short8*>(Wl + (set * 16 + nn) * WLSTR + quad * 8) = frag;
        }
    }
    barrier_lds();                 // Wl + Vt init visible

    consume(0);                    // rows 0..63 -> LDS
    issue(1);                      // chunk-1 loads in flight across attn
    __builtin_amdgcn_sched_barrier(0);
    barrier_lds();                 // rows 0..63 visible

    attn_tile(wv);                 // tiles 0..3   (chunks 1,1,2,2)
    consume(1);                    // rows 64..127
    issue(2);
    __builtin_amdgcn_sched_barrier(0);
    barrier_lds();                 // rows 0..127 visible

    attn_tile(4 + (wv ^ 1));       // tiles 4..7   (chunks 3,3,4,4)
    consume(2);                    // rows 128..191
    issue(3);
    __builtin_amdgcn_sched_barrier(0);
    barrier_lds();                 // rows 0..191 visible

    attn_tile(8 + (wv ^ 2));       // tiles 8..11  (chunks 6,6,5,5)
    consume(3);                    // rows 192..255
    barrier_lds();                 // all rows visible

    attn_tile(12 + (wv ^ 3));      // tiles 12..15 (chunks 8,8,7,7)
}

extern "C" void kernel_launch(void* const* d_in, const int* in_sizes, int n_in,
                              void* d_out, int out_size, void* d_ws, size_t ws_size,
                              hipStream_t stream)
{
    const float* x  = (const float*)d_in[0];
    const float* Wq = (const float*)d_in[1];
    const float* Wk = (const float*)d_in[2];
    const float* Wv = (const float*)d_in[3];
    float* out      = (float*)d_out;
    const int B = in_sizes[0] / (TT * CC);   // = 1024
    fused_head<<<dim3(B), dim3(256), 0, stream>>>(x, Wq, Wk, Wv, out);
}